// Round 1
// baseline (3720.187 us; speedup 1.0000x reference)
//
#include <hip/hip_runtime.h>
#include <math.h>

// Problem constants (B=4, S=2048, F=8, D=256, H=8, L=2, FF=1024, NSK=2000, DQ=64)
#define SEQ   2048
#define BATCH 4
#define NTOK  8192      // B*S
#define DMODEL 256
#define NHEAD 8
#define DHEAD 32
#define DFF   1024
#define NSKC  2000

// ---------------------------------------------------------------------------
// Kernel 1: build concat row [inter_e(256) | pat_e(64) | feat_e(64)] per token
// ---------------------------------------------------------------------------
__global__ __launch_bounds__(384) void concat_kernel(
    const int* __restrict__ interactions, const int* __restrict__ patterns,
    const float* __restrict__ ff, const float* __restrict__ inter_emb,
    const float* __restrict__ pattern_emb, const float* __restrict__ feat_W,
    const float* __restrict__ feat_b, float* __restrict__ out)
{
    int tok = blockIdx.x;
    int j = threadIdx.x;
    float v;
    if (j < 256) {
        v = inter_emb[(size_t)interactions[tok] * 256 + j];
    } else if (j < 320) {
        v = pattern_emb[patterns[tok] * 64 + (j - 256)];
    } else {
        int c = j - 320;
        float acc = feat_b[c];
#pragma unroll
        for (int f = 0; f < 8; f++) acc += ff[tok * 8 + f] * feat_W[f * 64 + c];
        v = acc;
    }
    out[(size_t)tok * 384 + j] = v;
}

// ---------------------------------------------------------------------------
// Kernel 2: x += tanh(elapsed*time_W + time_b) + (s/S)*pos_W + pos_b
// ---------------------------------------------------------------------------
__global__ __launch_bounds__(256) void addenc_kernel(
    float* __restrict__ x, const float* __restrict__ ff,
    const float* __restrict__ time_W, const float* __restrict__ time_b,
    const float* __restrict__ pos_W, const float* __restrict__ pos_b)
{
    int tok = blockIdx.x;
    int d = threadIdx.x;
    int s = tok & (SEQ - 1);
    float el = ff[tok * 8];  // forget_features[..., 0]
    float te = tanhf(el * time_W[d] + time_b[d]);
    float pe = ((float)s * (1.0f / (float)SEQ)) * pos_W[d] + pos_b[d];
    x[(size_t)tok * DMODEL + d] += te + pe;
}

// ---------------------------------------------------------------------------
// Generic fp32 tiled GEMM: C[M,N] = A[M,K] @ B[K,N] + bias[N], optional GELU.
// BM=BN=64, BK=16, 256 threads, 4x4 microtile. M%64==0, K%16==0 assumed.
// ---------------------------------------------------------------------------
__global__ __launch_bounds__(256) void gemm_kernel(
    const float* __restrict__ A, const float* __restrict__ Bm,
    const float* __restrict__ bias, float* __restrict__ C,
    int M, int N, int K, int gelu_flag)
{
    __shared__ float As[16][65];   // +1 pad
    __shared__ float Bs[16][64];
    int m0 = blockIdx.y * 64;
    int n0 = blockIdx.x * 64;
    int tid = threadIdx.x;
    int tx = tid & 15, ty = tid >> 4;
    int ar = tid >> 2, ac = (tid & 3) << 2;   // A loader: row 0..63, col4
    int br = tid >> 4, bc = (tid & 15) << 2;  // B loader: row 0..15, col4
    bool bfull = (n0 + 64 <= N);
    float acc[4][4] = {};

    for (int k0 = 0; k0 < K; k0 += 16) {
        float4 av = *(const float4*)&A[(size_t)(m0 + ar) * K + k0 + ac];
        As[ac + 0][ar] = av.x; As[ac + 1][ar] = av.y;
        As[ac + 2][ar] = av.z; As[ac + 3][ar] = av.w;
        if (bfull) {
            *(float4*)&Bs[br][bc] = *(const float4*)&Bm[(size_t)(k0 + br) * N + n0 + bc];
        } else {
#pragma unroll
            for (int j2 = 0; j2 < 4; j2++) {
                int n = n0 + bc + j2;
                Bs[br][bc + j2] = (n < N) ? Bm[(size_t)(k0 + br) * N + n] : 0.0f;
            }
        }
        __syncthreads();
#pragma unroll
        for (int kk = 0; kk < 16; kk++) {
            float a4[4], b4[4];
#pragma unroll
            for (int i = 0; i < 4; i++) a4[i] = As[kk][ty * 4 + i];
#pragma unroll
            for (int j2 = 0; j2 < 4; j2++) b4[j2] = Bs[kk][tx * 4 + j2];
#pragma unroll
            for (int i = 0; i < 4; i++)
#pragma unroll
                for (int j2 = 0; j2 < 4; j2++)
                    acc[i][j2] += a4[i] * b4[j2];
        }
        __syncthreads();
    }

#pragma unroll
    for (int i = 0; i < 4; i++) {
        int m = m0 + ty * 4 + i;
#pragma unroll
        for (int j2 = 0; j2 < 4; j2++) {
            int n = n0 + tx * 4 + j2;
            if (n < N) {
                float v = acc[i][j2] + bias[n];
                if (gelu_flag) v = 0.5f * v * (1.0f + erff(v * 0.70710678118654752f));
                C[(size_t)m * N + n] = v;
            }
        }
    }
}

// ---------------------------------------------------------------------------
// LayerNorm(x + r) in place: one block per token row (256 dims).
// ---------------------------------------------------------------------------
__global__ __launch_bounds__(256) void ln_kernel(
    float* __restrict__ x, const float* __restrict__ r,
    const float* __restrict__ g, const float* __restrict__ b)
{
    int tok = blockIdx.x;
    int d = threadIdx.x;
    float v = x[(size_t)tok * DMODEL + d] + r[(size_t)tok * DMODEL + d];
    float s1 = v, s2 = v * v;
#pragma unroll
    for (int off = 32; off > 0; off >>= 1) {
        s1 += __shfl_down(s1, off, 64);
        s2 += __shfl_down(s2, off, 64);
    }
    __shared__ float red1[4], red2[4];
    int wid = d >> 6, lane = d & 63;
    if (lane == 0) { red1[wid] = s1; red2[wid] = s2; }
    __syncthreads();
    s1 = red1[0] + red1[1] + red1[2] + red1[3];
    s2 = red2[0] + red2[1] + red2[2] + red2[3];
    float mean = s1 * (1.0f / 256.0f);
    float var = s2 * (1.0f / 256.0f) - mean * mean;
    float inv = rsqrtf(var + 1e-6f);
    x[(size_t)tok * DMODEL + d] = g[d] * (v - mean) * inv + b[d];
}

// ---------------------------------------------------------------------------
// Flash-style causal attention with kerple bias, max-free online softmax.
// grid (S/128, H, B), block 128: one thread per query row; K/V tiles in LDS.
// q,k,v,o layout: (B,S,H,DH) fp32.
// ---------------------------------------------------------------------------
__global__ __launch_bounds__(128) void attn_kernel(
    const float* __restrict__ q, const float* __restrict__ k,
    const float* __restrict__ v, const float* __restrict__ kp,
    const float* __restrict__ ka, float* __restrict__ o)
{
    int qt = blockIdx.x, h = blockIdx.y, b = blockIdx.z;
    int tid = threadIdx.x;
    int s = qt * 128 + tid;

    __shared__ float Kt[128][32];
    __shared__ float Vt[128][32];

    float p = log1pf(__expf(kp[h]));   // softplus
    float a = log1pf(__expf(ka[h]));
    const float inv_sqrt_dh = 0.17677669529663687f;  // 1/sqrt(32)

    float qreg[32];
    {
        const float4* qp = (const float4*)&q[((size_t)(b * SEQ + s) * NHEAD + h) * DHEAD];
#pragma unroll
        for (int i = 0; i < 8; i++) {
            float4 t4 = qp[i];
            qreg[4 * i] = t4.x; qreg[4 * i + 1] = t4.y;
            qreg[4 * i + 2] = t4.z; qreg[4 * i + 3] = t4.w;
        }
    }

    float acc[32] = {};
    float l = 0.0f;
    int nkt = qt + 1;

    for (int kt = 0; kt < nkt; kt++) {
        int t0 = kt * 128;
        __syncthreads();  // previous tile fully consumed
#pragma unroll
        for (int j = 0; j < 8; j++) {
            int idx = j * 128 + tid;       // 0..1023 float4 slots
            int tl = idx >> 3;
            int c4 = (idx & 7) * 4;
            size_t gbase = ((size_t)(b * SEQ + t0 + tl) * NHEAD + h) * DHEAD + c4;
            *(float4*)&Kt[tl][c4] = *(const float4*)&k[gbase];
            *(float4*)&Vt[tl][c4] = *(const float4*)&v[gbase];
        }
        __syncthreads();

        int tmax = (kt == qt) ? (tid + 1) : 128;  // causal: keys t0..s only
        for (int tt = 0; tt < tmax; tt++) {
            float dot = 0.0f;
#pragma unroll
            for (int kk = 0; kk < 32; kk++) dot += qreg[kk] * Kt[tt][kk];
            float dist = (float)(s - (t0 + tt));
            float sc = dot * inv_sqrt_dh - p * log1pf(a * dist);
            float e = __expf(sc);   // scores bounded; max-free softmax is safe
            l += e;
#pragma unroll
            for (int kk = 0; kk < 32; kk++) acc[kk] += e * Vt[tt][kk];
        }
    }

    float rl = 1.0f / l;
    float4* op = (float4*)&o[((size_t)(b * SEQ + s) * NHEAD + h) * DHEAD];
#pragma unroll
    for (int i = 0; i < 8; i++) {
        float4 t4;
        t4.x = acc[4 * i] * rl;     t4.y = acc[4 * i + 1] * rl;
        t4.z = acc[4 * i + 2] * rl; t4.w = acc[4 * i + 3] * rl;
        op[i] = t4;
    }
}

// ---------------------------------------------------------------------------
extern "C" void kernel_launch(void* const* d_in, const int* in_sizes, int n_in,
                              void* d_out, int out_size, void* d_ws, size_t ws_size,
                              hipStream_t stream) {
    const int*   interactions = (const int*)d_in[0];
    const int*   patterns     = (const int*)d_in[1];
    const float* ff           = (const float*)d_in[2];
    const float* inter_emb    = (const float*)d_in[3];
    const float* pattern_emb  = (const float*)d_in[4];
    const float* feat_W       = (const float*)d_in[5];
    const float* feat_b       = (const float*)d_in[6];
    const float* in_W         = (const float*)d_in[7];
    const float* in_b         = (const float*)d_in[8];
    const float* time_W       = (const float*)d_in[9];
    const float* time_b       = (const float*)d_in[10];
    const float* pos_W        = (const float*)d_in[11];
    const float* pos_b        = (const float*)d_in[12];
    const float* Wq           = (const float*)d_in[13];
    const float* bq           = (const float*)d_in[14];
    const float* Wk           = (const float*)d_in[15];
    const float* bk           = (const float*)d_in[16];
    const float* Wv           = (const float*)d_in[17];
    const float* bv           = (const float*)d_in[18];
    const float* Wo           = (const float*)d_in[19];
    const float* bo           = (const float*)d_in[20];
    const float* kerple_p     = (const float*)d_in[21];
    const float* kerple_a     = (const float*)d_in[22];
    const float* ln1_g        = (const float*)d_in[23];
    const float* ln1_b        = (const float*)d_in[24];
    const float* ln2_g        = (const float*)d_in[25];
    const float* ln2_b        = (const float*)d_in[26];
    const float* ffn_W1       = (const float*)d_in[27];
    const float* ffn_b1       = (const float*)d_in[28];
    const float* ffn_W2       = (const float*)d_in[29];
    const float* ffn_b2       = (const float*)d_in[30];
    const float* out_W        = (const float*)d_in[31];
    const float* out_b        = (const float*)d_in[32];
    float* out = (float*)d_out;

    // Workspace layout (floats). Total 6 * 2M floats = 48 MB.
    const size_t TOKD = (size_t)NTOK * DMODEL;  // 2,097,152
    float* ws   = (float*)d_ws;
    float* x    = ws;
    float* qb   = ws + 1 * TOKD;
    float* kb   = ws + 2 * TOKD;
    float* vb   = ws + 3 * TOKD;
    float* ob   = ws + 4 * TOKD;
    float* tmp  = ws + 5 * TOKD;
    float* h    = qb;      // 8192x1024 = exactly q..o region (dead by then)
    float* cbuf = qb;      // 8192x384 concat buffer (fits in q..k region)

    // Input projection: concat -> x, then add time/pos encodings.
    concat_kernel<<<NTOK, 384, 0, stream>>>(interactions, patterns, ff,
                                            inter_emb, pattern_emb, feat_W, feat_b, cbuf);
    gemm_kernel<<<dim3(4, 128), 256, 0, stream>>>(cbuf, in_W, in_b, x,
                                                  NTOK, DMODEL, 384, 0);
    addenc_kernel<<<NTOK, 256, 0, stream>>>(x, ff, time_W, time_b, pos_W, pos_b);

    for (int l = 0; l < 2; l++) {
        const float* Wq_l = Wq + (size_t)l * DMODEL * DMODEL;
        const float* Wk_l = Wk + (size_t)l * DMODEL * DMODEL;
        const float* Wv_l = Wv + (size_t)l * DMODEL * DMODEL;
        const float* Wo_l = Wo + (size_t)l * DMODEL * DMODEL;
        gemm_kernel<<<dim3(4, 128), 256, 0, stream>>>(x, Wq_l, bq + l * DMODEL, qb,
                                                      NTOK, DMODEL, DMODEL, 0);
        gemm_kernel<<<dim3(4, 128), 256, 0, stream>>>(x, Wk_l, bk + l * DMODEL, kb,
                                                      NTOK, DMODEL, DMODEL, 0);
        gemm_kernel<<<dim3(4, 128), 256, 0, stream>>>(x, Wv_l, bv + l * DMODEL, vb,
                                                      NTOK, DMODEL, DMODEL, 0);
        attn_kernel<<<dim3(SEQ / 128, NHEAD, BATCH), 128, 0, stream>>>(
            qb, kb, vb, kerple_p + l * NHEAD, kerple_a + l * NHEAD, ob);
        gemm_kernel<<<dim3(4, 128), 256, 0, stream>>>(ob, Wo_l, bo + l * DMODEL, tmp,
                                                      NTOK, DMODEL, DMODEL, 0);
        ln_kernel<<<NTOK, 256, 0, stream>>>(x, tmp, ln1_g + l * DMODEL, ln1_b + l * DMODEL);
        gemm_kernel<<<dim3(16, 128), 256, 0, stream>>>(
            x, ffn_W1 + (size_t)l * DMODEL * DFF, ffn_b1 + l * DFF, h,
            NTOK, DFF, DMODEL, 1);
        gemm_kernel<<<dim3(4, 128), 256, 0, stream>>>(
            h, ffn_W2 + (size_t)l * DMODEL * DFF, ffn_b2 + l * DMODEL, tmp,
            NTOK, DMODEL, DFF, 0);
        ln_kernel<<<NTOK, 256, 0, stream>>>(x, tmp, ln2_g + l * DMODEL, ln2_b + l * DMODEL);
    }

    // Output projection: x @ out_W (256x2000) + out_b
    gemm_kernel<<<dim3(32, 128), 256, 0, stream>>>(x, out_W, out_b, out,
                                                   NTOK, NSKC, DMODEL, 0);
}

// Round 2
// 1618.537 us; speedup vs baseline: 2.2985x; 2.2985x over previous
//
#include <hip/hip_runtime.h>
#include <math.h>

// Problem constants (B=4, S=2048, F=8, D=256, H=8, L=2, FF=1024, NSK=2000, DQ=64)
#define SEQ   2048
#define BATCH 4
#define NTOK  8192      // B*S
#define DMODEL 256
#define NHEAD 8
#define DHEAD 32
#define DFF   1024
#define NSKC  2000

// ---------------------------------------------------------------------------
// Kernel 1: build concat row [inter_e(256) | pat_e(64) | feat_e(64)] per token
// ---------------------------------------------------------------------------
__global__ __launch_bounds__(384) void concat_kernel(
    const int* __restrict__ interactions, const int* __restrict__ patterns,
    const float* __restrict__ ff, const float* __restrict__ inter_emb,
    const float* __restrict__ pattern_emb, const float* __restrict__ feat_W,
    const float* __restrict__ feat_b, float* __restrict__ out)
{
    int tok = blockIdx.x;
    int j = threadIdx.x;
    float v;
    if (j < 256) {
        v = inter_emb[(size_t)interactions[tok] * 256 + j];
    } else if (j < 320) {
        v = pattern_emb[patterns[tok] * 64 + (j - 256)];
    } else {
        int c = j - 320;
        float acc = feat_b[c];
#pragma unroll
        for (int f = 0; f < 8; f++) acc += ff[tok * 8 + f] * feat_W[f * 64 + c];
        v = acc;
    }
    out[(size_t)tok * 384 + j] = v;
}

// ---------------------------------------------------------------------------
// Kernel 2: x += tanh(elapsed*time_W + time_b) + (s/S)*pos_W + pos_b
// ---------------------------------------------------------------------------
__global__ __launch_bounds__(256) void addenc_kernel(
    float* __restrict__ x, const float* __restrict__ ff,
    const float* __restrict__ time_W, const float* __restrict__ time_b,
    const float* __restrict__ pos_W, const float* __restrict__ pos_b)
{
    int tok = blockIdx.x;
    int d = threadIdx.x;
    int s = tok & (SEQ - 1);
    float el = ff[tok * 8];  // forget_features[..., 0]
    float te = tanhf(el * time_W[d] + time_b[d]);
    float pe = ((float)s * (1.0f / (float)SEQ)) * pos_W[d] + pos_b[d];
    x[(size_t)tok * DMODEL + d] += te + pe;
}

// ---------------------------------------------------------------------------
// Generic fp32 tiled GEMM: C[M,N] = A[M,K] @ B[K,N] + bias[N], optional GELU.
// BM=BN=64, BK=16, 256 threads, 4x4 microtile. M%64==0, K%16==0 assumed.
// ---------------------------------------------------------------------------
__global__ __launch_bounds__(256) void gemm_kernel(
    const float* __restrict__ A, const float* __restrict__ Bm,
    const float* __restrict__ bias, float* __restrict__ C,
    int M, int N, int K, int gelu_flag)
{
    __shared__ float As[16][65];   // +1 pad
    __shared__ float Bs[16][64];
    int m0 = blockIdx.y * 64;
    int n0 = blockIdx.x * 64;
    int tid = threadIdx.x;
    int tx = tid & 15, ty = tid >> 4;
    int ar = tid >> 2, ac = (tid & 3) << 2;   // A loader: row 0..63, col4
    int br = tid >> 4, bc = (tid & 15) << 2;  // B loader: row 0..15, col4
    bool bfull = (n0 + 64 <= N);
    float acc[4][4] = {};

    for (int k0 = 0; k0 < K; k0 += 16) {
        float4 av = *(const float4*)&A[(size_t)(m0 + ar) * K + k0 + ac];
        As[ac + 0][ar] = av.x; As[ac + 1][ar] = av.y;
        As[ac + 2][ar] = av.z; As[ac + 3][ar] = av.w;
        if (bfull) {
            *(float4*)&Bs[br][bc] = *(const float4*)&Bm[(size_t)(k0 + br) * N + n0 + bc];
        } else {
#pragma unroll
            for (int j2 = 0; j2 < 4; j2++) {
                int n = n0 + bc + j2;
                Bs[br][bc + j2] = (n < N) ? Bm[(size_t)(k0 + br) * N + n] : 0.0f;
            }
        }
        __syncthreads();
#pragma unroll
        for (int kk = 0; kk < 16; kk++) {
            float a4[4], b4[4];
#pragma unroll
            for (int i = 0; i < 4; i++) a4[i] = As[kk][ty * 4 + i];
#pragma unroll
            for (int j2 = 0; j2 < 4; j2++) b4[j2] = Bs[kk][tx * 4 + j2];
#pragma unroll
            for (int i = 0; i < 4; i++)
#pragma unroll
                for (int j2 = 0; j2 < 4; j2++)
                    acc[i][j2] += a4[i] * b4[j2];
        }
        __syncthreads();
    }

#pragma unroll
    for (int i = 0; i < 4; i++) {
        int m = m0 + ty * 4 + i;
#pragma unroll
        for (int j2 = 0; j2 < 4; j2++) {
            int n = n0 + tx * 4 + j2;
            if (n < N) {
                float v = acc[i][j2] + bias[n];
                if (gelu_flag) v = 0.5f * v * (1.0f + erff(v * 0.70710678118654752f));
                C[(size_t)m * N + n] = v;
            }
        }
    }
}

// ---------------------------------------------------------------------------
// LayerNorm(x + r) in place: one block per token row (256 dims).
// ---------------------------------------------------------------------------
__global__ __launch_bounds__(256) void ln_kernel(
    float* __restrict__ x, const float* __restrict__ r,
    const float* __restrict__ g, const float* __restrict__ b)
{
    int tok = blockIdx.x;
    int d = threadIdx.x;
    float v = x[(size_t)tok * DMODEL + d] + r[(size_t)tok * DMODEL + d];
    float s1 = v, s2 = v * v;
#pragma unroll
    for (int off = 32; off > 0; off >>= 1) {
        s1 += __shfl_down(s1, off, 64);
        s2 += __shfl_down(s2, off, 64);
    }
    __shared__ float red1[4], red2[4];
    int wid = d >> 6, lane = d & 63;
    if (lane == 0) { red1[wid] = s1; red2[wid] = s2; }
    __syncthreads();
    s1 = red1[0] + red1[1] + red1[2] + red1[3];
    s2 = red2[0] + red2[1] + red2[2] + red2[3];
    float mean = s1 * (1.0f / 256.0f);
    float var = s2 * (1.0f / 256.0f) - mean * mean;
    float inv = rsqrtf(var + 1e-6f);
    x[(size_t)tok * DMODEL + d] = g[d] * (v - mean) * inv + b[d];
}

// ---------------------------------------------------------------------------
// Flash-style causal attention with kerple bias, max-free online softmax.
// v2: block=256 covers 64 queries; 8 threads per query (keys split mod 8),
// 2 queries per thread (s and s+32). K/V tiles (128 keys) staged in LDS with
// rows padded to 36 floats (stride 144B: float4-aligned, 8 distinct sub-lanes
// hit 8 distinct banks -> conflict-free). Kerple bias -p*log1p(a*dist) is a
// 2048-entry LDS lookup table. Max-free softmax (scores bounded) -> partial
// (acc,l) sums combine by pure addition via shfl over the 8 sub-lanes.
// q,k,v,o layout: (B,S,H,DH) fp32.
// ---------------------------------------------------------------------------
__global__ __launch_bounds__(256) void attn_kernel(
    const float* __restrict__ q, const float* __restrict__ k,
    const float* __restrict__ v, const float* __restrict__ kp,
    const float* __restrict__ ka, float* __restrict__ o)
{
    int qt = blockIdx.x, h = blockIdx.y, b = blockIdx.z;
    int tid = threadIdx.x;
    int qidx = tid >> 3;     // 0..31
    int sub  = tid & 7;      // key-subset within query
    int s0 = qt * 64;
    int s1 = s0 + qidx;      // query 1
    int s2 = s1 + 32;        // query 2

    __shared__ float Kt[128][36];
    __shared__ float Vt[128][36];
    __shared__ float tab[2048];

    float p = log1pf(__expf(kp[h]));   // softplus
    float a = log1pf(__expf(ka[h]));
    for (int i = tid; i < 2048; i += 256) tab[i] = -p * log1pf(a * (float)i);

    const float scale = 0.17677669529663687f;  // 1/sqrt(32)

    float q1[32], q2[32];
    {
        const float4* qp1 = (const float4*)&q[((size_t)(b * SEQ + s1) * NHEAD + h) * DHEAD];
        const float4* qp2 = (const float4*)&q[((size_t)(b * SEQ + s2) * NHEAD + h) * DHEAD];
#pragma unroll
        for (int i = 0; i < 8; i++) {
            float4 t1 = qp1[i], t2 = qp2[i];
            q1[4*i] = t1.x; q1[4*i+1] = t1.y; q1[4*i+2] = t1.z; q1[4*i+3] = t1.w;
            q2[4*i] = t2.x; q2[4*i+1] = t2.y; q2[4*i+2] = t2.z; q2[4*i+3] = t2.w;
        }
    }

    float acc1[32] = {}, acc2[32] = {};
    float l1 = 0.0f, l2 = 0.0f;
    int nkt = (s0 + 63) / 128 + 1;   // tiles covering keys 0..s0+63

    for (int kt = 0; kt < nkt; kt++) {
        int t0 = kt * 128;
        __syncthreads();  // previous tile fully consumed (also covers tab fill)
#pragma unroll
        for (int j = 0; j < 4; j++) {
            int idx = j * 256 + tid;   // 0..1023 float4 slots
            int tl = idx >> 3;
            int c4 = (idx & 7) * 4;
            size_t gbase = ((size_t)(b * SEQ + t0 + tl) * NHEAD + h) * DHEAD + c4;
            *(float4*)&Kt[tl][c4] = *(const float4*)&k[gbase];
            *(float4*)&Vt[tl][c4] = *(const float4*)&v[gbase];
        }
        __syncthreads();

        int k1 = s1 - t0 + 1; if (k1 > 128) k1 = 128;  // causal bounds
        int k2 = s2 - t0 + 1; if (k2 > 128) k2 = 128;

        for (int tt = sub; tt < k2; tt += 8) {
            const float* kr = &Kt[tt][0];
            float d1a = 0.f, d1b = 0.f, d2a = 0.f, d2b = 0.f;
#pragma unroll
            for (int j = 0; j < 8; j += 2) {
                float4 ka4 = *(const float4*)(kr + 4 * j);
                float4 kb4 = *(const float4*)(kr + 4 * j + 4);
                d1a += q1[4*j+0]*ka4.x; d1a += q1[4*j+1]*ka4.y;
                d1a += q1[4*j+2]*ka4.z; d1a += q1[4*j+3]*ka4.w;
                d2a += q2[4*j+0]*ka4.x; d2a += q2[4*j+1]*ka4.y;
                d2a += q2[4*j+2]*ka4.z; d2a += q2[4*j+3]*ka4.w;
                d1b += q1[4*j+4]*kb4.x; d1b += q1[4*j+5]*kb4.y;
                d1b += q1[4*j+6]*kb4.z; d1b += q1[4*j+7]*kb4.w;
                d2b += q2[4*j+4]*kb4.x; d2b += q2[4*j+5]*kb4.y;
                d2b += q2[4*j+6]*kb4.z; d2b += q2[4*j+7]*kb4.w;
            }
            int dist2 = s2 - (t0 + tt);
            float e2 = __expf((d2a + d2b) * scale + tab[dist2]);
            l2 += e2;
            float e1 = 0.0f;
            if (tt < k1) {   // guard keeps tab read in-bounds (dist2-32 >= 0)
                e1 = __expf((d1a + d1b) * scale + tab[dist2 - 32]);
                l1 += e1;
            }
            const float* vr = &Vt[tt][0];
#pragma unroll
            for (int j = 0; j < 8; j++) {
                float4 vv = *(const float4*)(vr + 4 * j);
                acc2[4*j+0] += e2 * vv.x; acc2[4*j+1] += e2 * vv.y;
                acc2[4*j+2] += e2 * vv.z; acc2[4*j+3] += e2 * vv.w;
                acc1[4*j+0] += e1 * vv.x; acc1[4*j+1] += e1 * vv.y;
                acc1[4*j+2] += e1 * vv.z; acc1[4*j+3] += e1 * vv.w;
            }
        }
    }

    // combine the 8 key-subset partials (pure sums — max-free softmax)
#pragma unroll
    for (int off = 4; off >= 1; off >>= 1) {
        l1 += __shfl_down(l1, off, 8);
        l2 += __shfl_down(l2, off, 8);
#pragma unroll
        for (int i = 0; i < 32; i++) {
            acc1[i] += __shfl_down(acc1[i], off, 8);
            acc2[i] += __shfl_down(acc2[i], off, 8);
        }
    }

    if (sub == 0) {
        float r1 = 1.0f / l1, r2 = 1.0f / l2;
        float4* o1 = (float4*)&o[((size_t)(b * SEQ + s1) * NHEAD + h) * DHEAD];
        float4* o2 = (float4*)&o[((size_t)(b * SEQ + s2) * NHEAD + h) * DHEAD];
#pragma unroll
        for (int i = 0; i < 8; i++) {
            float4 w1, w2;
            w1.x = acc1[4*i]*r1;   w1.y = acc1[4*i+1]*r1;
            w1.z = acc1[4*i+2]*r1; w1.w = acc1[4*i+3]*r1;
            w2.x = acc2[4*i]*r2;   w2.y = acc2[4*i+1]*r2;
            w2.z = acc2[4*i+2]*r2; w2.w = acc2[4*i+3]*r2;
            o1[i] = w1; o2[i] = w2;
        }
    }
}

// ---------------------------------------------------------------------------
extern "C" void kernel_launch(void* const* d_in, const int* in_sizes, int n_in,
                              void* d_out, int out_size, void* d_ws, size_t ws_size,
                              hipStream_t stream) {
    const int*   interactions = (const int*)d_in[0];
    const int*   patterns     = (const int*)d_in[1];
    const float* ff           = (const float*)d_in[2];
    const float* inter_emb    = (const float*)d_in[3];
    const float* pattern_emb  = (const float*)d_in[4];
    const float* feat_W       = (const float*)d_in[5];
    const float* feat_b       = (const float*)d_in[6];
    const float* in_W         = (const float*)d_in[7];
    const float* in_b         = (const float*)d_in[8];
    const float* time_W       = (const float*)d_in[9];
    const float* time_b       = (const float*)d_in[10];
    const float* pos_W        = (const float*)d_in[11];
    const float* pos_b        = (const float*)d_in[12];
    const float* Wq           = (const float*)d_in[13];
    const float* bq           = (const float*)d_in[14];
    const float* Wk           = (const float*)d_in[15];
    const float* bk           = (const float*)d_in[16];
    const float* Wv           = (const float*)d_in[17];
    const float* bv           = (const float*)d_in[18];
    const float* Wo           = (const float*)d_in[19];
    const float* bo           = (const float*)d_in[20];
    const float* kerple_p     = (const float*)d_in[21];
    const float* kerple_a     = (const float*)d_in[22];
    const float* ln1_g        = (const float*)d_in[23];
    const float* ln1_b        = (const float*)d_in[24];
    const float* ln2_g        = (const float*)d_in[25];
    const float* ln2_b        = (const float*)d_in[26];
    const float* ffn_W1       = (const float*)d_in[27];
    const float* ffn_b1       = (const float*)d_in[28];
    const float* ffn_W2       = (const float*)d_in[29];
    const float* ffn_b2       = (const float*)d_in[30];
    const float* out_W        = (const float*)d_in[31];
    const float* out_b        = (const float*)d_in[32];
    float* out = (float*)d_out;

    // Workspace layout (floats). Total 6 * 2M floats = 48 MB.
    const size_t TOKD = (size_t)NTOK * DMODEL;  // 2,097,152
    float* ws   = (float*)d_ws;
    float* x    = ws;
    float* qb   = ws + 1 * TOKD;
    float* kb   = ws + 2 * TOKD;
    float* vb   = ws + 3 * TOKD;
    float* ob   = ws + 4 * TOKD;
    float* tmp  = ws + 5 * TOKD;
    float* h    = qb;      // 8192x1024 = exactly q..o region (dead by then)
    float* cbuf = qb;      // 8192x384 concat buffer (fits in q..k region)

    // Input projection: concat -> x, then add time/pos encodings.
    concat_kernel<<<NTOK, 384, 0, stream>>>(interactions, patterns, ff,
                                            inter_emb, pattern_emb, feat_W, feat_b, cbuf);
    gemm_kernel<<<dim3(4, 128), 256, 0, stream>>>(cbuf, in_W, in_b, x,
                                                  NTOK, DMODEL, 384, 0);
    addenc_kernel<<<NTOK, 256, 0, stream>>>(x, ff, time_W, time_b, pos_W, pos_b);

    for (int l = 0; l < 2; l++) {
        const float* Wq_l = Wq + (size_t)l * DMODEL * DMODEL;
        const float* Wk_l = Wk + (size_t)l * DMODEL * DMODEL;
        const float* Wv_l = Wv + (size_t)l * DMODEL * DMODEL;
        const float* Wo_l = Wo + (size_t)l * DMODEL * DMODEL;
        gemm_kernel<<<dim3(4, 128), 256, 0, stream>>>(x, Wq_l, bq + l * DMODEL, qb,
                                                      NTOK, DMODEL, DMODEL, 0);
        gemm_kernel<<<dim3(4, 128), 256, 0, stream>>>(x, Wk_l, bk + l * DMODEL, kb,
                                                      NTOK, DMODEL, DMODEL, 0);
        gemm_kernel<<<dim3(4, 128), 256, 0, stream>>>(x, Wv_l, bv + l * DMODEL, vb,
                                                      NTOK, DMODEL, DMODEL, 0);
        attn_kernel<<<dim3(SEQ / 64, NHEAD, BATCH), 256, 0, stream>>>(
            qb, kb, vb, kerple_p + l * NHEAD, kerple_a + l * NHEAD, ob);
        gemm_kernel<<<dim3(4, 128), 256, 0, stream>>>(ob, Wo_l, bo + l * DMODEL, tmp,
                                                      NTOK, DMODEL, DMODEL, 0);
        ln_kernel<<<NTOK, 256, 0, stream>>>(x, tmp, ln1_g + l * DMODEL, ln1_b + l * DMODEL);
        gemm_kernel<<<dim3(16, 128), 256, 0, stream>>>(
            x, ffn_W1 + (size_t)l * DMODEL * DFF, ffn_b1 + l * DFF, h,
            NTOK, DFF, DMODEL, 1);
        gemm_kernel<<<dim3(4, 128), 256, 0, stream>>>(
            h, ffn_W2 + (size_t)l * DMODEL * DFF, ffn_b2 + l * DMODEL, tmp,
            NTOK, DMODEL, DFF, 0);
        ln_kernel<<<NTOK, 256, 0, stream>>>(x, tmp, ln2_g + l * DMODEL, ln2_b + l * DMODEL);
    }

    // Output projection: x @ out_W (256x2000) + out_b
    gemm_kernel<<<dim3(32, 128), 256, 0, stream>>>(x, out_W, out_b, out,
                                                   NTOK, NSKC, DMODEL, 0);
}

// Round 3
// 547.284 us; speedup vs baseline: 6.7975x; 2.9574x over previous
//
#include <hip/hip_runtime.h>
#include <math.h>

// B=4, S=2048, F=8, D=256, H=8, L=2, FF=1024, NSK=2000
#define SEQ   2048
#define BATCH 4
#define NTOK  8192
#define DM    256
#define NHD   8
#define DHD   32
#define DFF   1024
#define NSKC  2000

typedef __attribute__((ext_vector_type(8))) short short8;
typedef __attribute__((ext_vector_type(4))) float f32x4;
typedef unsigned short ushort_t;

__device__ __forceinline__ ushort_t f2bf(float x) {
    union { float f; unsigned u; } c; c.f = x;
    unsigned r = c.u + 0x7FFFu + ((c.u >> 16) & 1u);
    return (ushort_t)(r >> 16);
}

// ---------------------------------------------------------------------------
// Weight conversion: dst[n][k] = bf16(src[k][n]) (transpose), zero-pad n>=N.
// ---------------------------------------------------------------------------
struct ConvSeg { const float* src; ushort_t* dst; int K; int N; int Npad; };
struct ConvArgs { ConvSeg s[14]; };

__global__ __launch_bounds__(256) void convert_kernel(ConvArgs args) {
    ConvSeg sg = args.s[blockIdx.y];
    int e = blockIdx.x * 256 + threadIdx.x;
    int tot = sg.Npad * sg.K;
    if (e >= tot) return;
    int n = e / sg.K;
    int k = e - n * sg.K;
    float v = (n < sg.N) ? sg.src[(size_t)k * sg.N + n] : 0.0f;
    sg.dst[e] = f2bf(v);
}

// ---------------------------------------------------------------------------
// concat row [inter_e(256) | pat_e(64) | feat_e(64)] -> bf16
// ---------------------------------------------------------------------------
__global__ __launch_bounds__(384) void concat_kernel(
    const int* __restrict__ interactions, const int* __restrict__ patterns,
    const float* __restrict__ ff, const float* __restrict__ inter_emb,
    const float* __restrict__ pattern_emb, const float* __restrict__ feat_W,
    const float* __restrict__ feat_b, ushort_t* __restrict__ out)
{
    int tok = blockIdx.x;
    int j = threadIdx.x;
    float v;
    if (j < 256) {
        v = inter_emb[(size_t)interactions[tok] * 256 + j];
    } else if (j < 320) {
        v = pattern_emb[patterns[tok] * 64 + (j - 256)];
    } else {
        int c = j - 320;
        float acc = feat_b[c];
#pragma unroll
        for (int f = 0; f < 8; f++) acc += ff[tok * 8 + f] * feat_W[f * 64 + c];
        v = acc;
    }
    out[(size_t)tok * 384 + j] = f2bf(v);
}

// ---------------------------------------------------------------------------
// x += tanh(el*time_W+time_b) + pos*pos_W+pos_b ; write fp32 + bf16 copies
// ---------------------------------------------------------------------------
__global__ __launch_bounds__(256) void addenc_kernel(
    float* __restrict__ x, ushort_t* __restrict__ xb, const float* __restrict__ ff,
    const float* __restrict__ time_W, const float* __restrict__ time_b,
    const float* __restrict__ pos_W, const float* __restrict__ pos_b)
{
    int tok = blockIdx.x;
    int d = threadIdx.x;
    int s = tok & (SEQ - 1);
    float el = ff[tok * 8];
    float te = tanhf(el * time_W[d] + time_b[d]);
    float pe = ((float)s * (1.0f / (float)SEQ)) * pos_W[d] + pos_b[d];
    size_t idx = (size_t)tok * DM + d;
    float nv = x[idx] + te + pe;
    x[idx] = nv;
    xb[idx] = f2bf(nv);
}

// ---------------------------------------------------------------------------
// LayerNorm(x + r) in place; also writes bf16 copy.
// ---------------------------------------------------------------------------
__global__ __launch_bounds__(256) void ln_kernel(
    float* __restrict__ x, const float* __restrict__ r,
    const float* __restrict__ g, const float* __restrict__ b,
    ushort_t* __restrict__ xb)
{
    int tok = blockIdx.x;
    int d = threadIdx.x;
    size_t idx = (size_t)tok * DM + d;
    float v = x[idx] + r[idx];
    float s1 = v, s2 = v * v;
#pragma unroll
    for (int off = 32; off > 0; off >>= 1) {
        s1 += __shfl_down(s1, off, 64);
        s2 += __shfl_down(s2, off, 64);
    }
    __shared__ float red1[4], red2[4];
    int wid = d >> 6, lane = d & 63;
    if (lane == 0) { red1[wid] = s1; red2[wid] = s2; }
    __syncthreads();
    s1 = red1[0] + red1[1] + red1[2] + red1[3];
    s2 = red2[0] + red2[1] + red2[2] + red2[3];
    float mean = s1 * (1.0f / 256.0f);
    float var = s2 * (1.0f / 256.0f) - mean * mean;
    float inv = rsqrtf(var + 1e-6f);
    float nv = g[d] * (v - mean) * inv + b[d];
    x[idx] = nv;
    xb[idx] = f2bf(nv);
}

// ---------------------------------------------------------------------------
// bf16 MFMA GEMM: C[M,N] = A[M,K](bf16,row-major) @ Bt[N,K](bf16)^T + bias.
// BM=128, BN=64, BK=32; 256 threads = 4 waves, each 32(m)x64(n), 8 mfma/iter.
// LDS rows padded to 40 elems (80B) -> 2-way-free ds_read_b128 frag reads.
// mode 0: fp32 out + bias          mode 1: gelu -> bf16 out
// mode 2: QKV epilogue (q,k (B,H,S,DH) bf16; v^T (B,H,DH,S) bf16)
// mode 3: fp32 out + bias, col guard n < Nreal, row stride Nreal
// ---------------------------------------------------------------------------
__global__ __launch_bounds__(256) void gemm_bf16(
    const ushort_t* __restrict__ A, const ushort_t* __restrict__ Bt,
    int M, int N, int K, int mode,
    float* __restrict__ Cf, ushort_t* __restrict__ Cb,
    ushort_t* __restrict__ Ck, ushort_t* __restrict__ Cv,
    const float* __restrict__ b0, const float* __restrict__ b1,
    const float* __restrict__ b2, int Nreal)
{
    __shared__ ushort_t As[128][40];
    __shared__ ushort_t Bs[64][40];
    int m0 = blockIdx.y * 128, n0 = blockIdx.x * 64;
    int tid = threadIdx.x;
    int wv = tid >> 6, lane = tid & 63;
    int quad = lane >> 4, l16 = lane & 15;
    int srow = tid >> 2, sc = (tid & 3) << 3;   // staging: row, elem-offset (8 bf16 = 16B)

    f32x4 acc[2][4];
#pragma unroll
    for (int i = 0; i < 2; i++)
#pragma unroll
        for (int j = 0; j < 4; j++) acc[i][j] = (f32x4){0.f, 0.f, 0.f, 0.f};

    int msub = wv * 32;
    for (int k0 = 0; k0 < K; k0 += 32) {
        __syncthreads();
        uint4 a0 = *(const uint4*)&A[(size_t)(m0 + srow) * K + k0 + sc];
        uint4 a1 = *(const uint4*)&A[(size_t)(m0 + 64 + srow) * K + k0 + sc];
        uint4 bb = *(const uint4*)&Bt[(size_t)(n0 + srow) * K + k0 + sc];
        *(uint4*)&As[srow][sc] = a0;
        *(uint4*)&As[64 + srow][sc] = a1;
        *(uint4*)&Bs[srow][sc] = bb;
        __syncthreads();
        short8 af0 = *(const short8*)&As[msub + l16][quad * 8];
        short8 af1 = *(const short8*)&As[msub + 16 + l16][quad * 8];
        short8 bf0 = *(const short8*)&Bs[l16][quad * 8];
        short8 bf1 = *(const short8*)&Bs[16 + l16][quad * 8];
        short8 bf2 = *(const short8*)&Bs[32 + l16][quad * 8];
        short8 bf3 = *(const short8*)&Bs[48 + l16][quad * 8];
        acc[0][0] = __builtin_amdgcn_mfma_f32_16x16x32_bf16(af0, bf0, acc[0][0], 0, 0, 0);
        acc[0][1] = __builtin_amdgcn_mfma_f32_16x16x32_bf16(af0, bf1, acc[0][1], 0, 0, 0);
        acc[0][2] = __builtin_amdgcn_mfma_f32_16x16x32_bf16(af0, bf2, acc[0][2], 0, 0, 0);
        acc[0][3] = __builtin_amdgcn_mfma_f32_16x16x32_bf16(af0, bf3, acc[0][3], 0, 0, 0);
        acc[1][0] = __builtin_amdgcn_mfma_f32_16x16x32_bf16(af1, bf0, acc[1][0], 0, 0, 0);
        acc[1][1] = __builtin_amdgcn_mfma_f32_16x16x32_bf16(af1, bf1, acc[1][1], 0, 0, 0);
        acc[1][2] = __builtin_amdgcn_mfma_f32_16x16x32_bf16(af1, bf2, acc[1][2], 0, 0, 0);
        acc[1][3] = __builtin_amdgcn_mfma_f32_16x16x32_bf16(af1, bf3, acc[1][3], 0, 0, 0);
    }

#pragma unroll
    for (int mt = 0; mt < 2; mt++) {
#pragma unroll
        for (int nt = 0; nt < 4; nt++) {
            int n = n0 + nt * 16 + l16;
#pragma unroll
            for (int r = 0; r < 4; r++) {
                int m = m0 + msub + mt * 16 + quad * 4 + r;
                float v = acc[mt][nt][r];
                if (mode == 0) {
                    Cf[(size_t)m * N + n] = v + b0[n];
                } else if (mode == 1) {
                    float t = v + b0[n];
                    t = 0.5f * t * (1.0f + erff(t * 0.70710678118654752f));
                    Cb[(size_t)m * N + n] = f2bf(t);
                } else if (mode == 3) {
                    if (n < Nreal) Cf[(size_t)m * Nreal + n] = v + b0[n];
                } else {
                    int which = n >> 8, idx = n & 255;
                    int hh = idx >> 5, d = idx & 31;
                    int s = m & (SEQ - 1), b = m >> 11;
                    if (which == 0)
                        Cb[(((size_t)(b * NHD + hh)) * SEQ + s) * DHD + d] = f2bf(v + b0[idx]);
                    else if (which == 1)
                        Ck[(((size_t)(b * NHD + hh)) * SEQ + s) * DHD + d] = f2bf(v + b1[idx]);
                    else
                        Cv[(((size_t)(b * NHD + hh)) * DHD + d) * SEQ + s] = f2bf(v + b2[idx]);
                }
            }
        }
    }
}

// ---------------------------------------------------------------------------
// MFMA flash attention. One wave per 16-query tile; 32 keys per chunk.
// Q,K bf16 (B,H,S,DH); V^T bf16 (B,H,DH,S); out bf16 (token, 256).
// QK^T: 2 mfma (A=Q frag, B=K frag); kerple bias from LDS table; max-free
// softmax; P (16x32) C->A layout via per-wave LDS (in-wave lgkmcnt wait,
// NO block barrier: waves have divergent trip counts); PV: 2 mfma vs V^T.
// ---------------------------------------------------------------------------
__global__ __launch_bounds__(256) void attn_mfma(
    const ushort_t* __restrict__ qb, const ushort_t* __restrict__ kb,
    const ushort_t* __restrict__ vtb, const float* __restrict__ kp,
    const float* __restrict__ ka, ushort_t* __restrict__ ob)
{
    int h = blockIdx.y, b = blockIdx.z;
    int tid = threadIdx.x, wv = tid >> 6, lane = tid & 63;
    int quad = lane >> 4, l16 = lane & 15;
    __shared__ float tab[SEQ];
    __shared__ ushort_t P[4][16 * 40];   // per-wave 16 rows x 40 elems (80B rows)

    float pp = log1pf(__expf(kp[h]));    // softplus
    float aa = log1pf(__expf(ka[h]));
    for (int i = tid; i < SEQ; i += 256) tab[i] = -pp * log1pf(aa * (float)i);
    __syncthreads();

    int bh = b * NHD + h;
    const ushort_t* Qh = qb + (size_t)bh * SEQ * DHD;
    const ushort_t* Kh = kb + (size_t)bh * SEQ * DHD;
    const ushort_t* Vh = vtb + (size_t)bh * DHD * SEQ;

    int qt = wv * 32 + blockIdx.x;       // 0..127
    int q0 = qt * 16;
    const float scale = 0.17677669529663687f;   // 1/sqrt(32)

    short8 qf = *(const short8*)&Qh[(q0 + l16) * DHD + quad * 8];
    f32x4 o0 = (f32x4){0.f, 0.f, 0.f, 0.f};
    f32x4 o1 = (f32x4){0.f, 0.f, 0.f, 0.f};
    float ls[4] = {0.f, 0.f, 0.f, 0.f};
    ushort_t* Pw = &P[wv][0];
    int qsr = q0 + quad * 4;

    int nch = (qt + 2) >> 1;             // ceil((16*qt+16)/32)
    for (int ch = 0; ch < nch; ch++) {
        int k0 = ch * 32;
        short8 kf0 = *(const short8*)&Kh[(k0 + l16) * DHD + quad * 8];
        short8 kf1 = *(const short8*)&Kh[(k0 + 16 + l16) * DHD + quad * 8];
        f32x4 z = (f32x4){0.f, 0.f, 0.f, 0.f};
        f32x4 s0 = __builtin_amdgcn_mfma_f32_16x16x32_bf16(qf, kf0, z, 0, 0, 0);
        f32x4 s1 = __builtin_amdgcn_mfma_f32_16x16x32_bf16(qf, kf1, z, 0, 0, 0);
#pragma unroll
        for (int r = 0; r < 4; r++) {
            int qs = qsr + r;
            int d0 = qs - (k0 + l16);
            int d1 = d0 - 16;
            float e0 = 0.f, e1 = 0.f;
            if (d0 >= 0) e0 = __expf(s0[r] * scale + tab[d0]);
            if (d1 >= 0) e1 = __expf(s1[r] * scale + tab[d1]);
            ls[r] += e0 + e1;
            Pw[(quad * 4 + r) * 40 + l16]      = f2bf(e0);
            Pw[(quad * 4 + r) * 40 + 16 + l16] = f2bf(e1);
        }
        __builtin_amdgcn_s_waitcnt(0xC07F);     // lgkmcnt(0): P writes visible
        __builtin_amdgcn_wave_barrier();        // pin write->read order
        short8 pf  = *(const short8*)&Pw[l16 * 40 + quad * 8];
        short8 vf0 = *(const short8*)&Vh[l16 * SEQ + k0 + quad * 8];
        short8 vf1 = *(const short8*)&Vh[(16 + l16) * SEQ + k0 + quad * 8];
        o0 = __builtin_amdgcn_mfma_f32_16x16x32_bf16(pf, vf0, o0, 0, 0, 0);
        o1 = __builtin_amdgcn_mfma_f32_16x16x32_bf16(pf, vf1, o1, 0, 0, 0);
    }

#pragma unroll
    for (int r = 0; r < 4; r++) {
#pragma unroll
        for (int off = 1; off < 16; off <<= 1)
            ls[r] += __shfl_xor(ls[r], off, 16);
    }
#pragma unroll
    for (int r = 0; r < 4; r++) {
        int qs = qsr + r;
        float rl = 1.0f / ls[r];
        size_t base = ((size_t)(b * SEQ + qs)) * DM + h * DHD;
        ob[base + l16]      = f2bf(o0[r] * rl);
        ob[base + 16 + l16] = f2bf(o1[r] * rl);
    }
}

// ---------------------------------------------------------------------------
extern "C" void kernel_launch(void* const* d_in, const int* in_sizes, int n_in,
                              void* d_out, int out_size, void* d_ws, size_t ws_size,
                              hipStream_t stream) {
    const int*   interactions = (const int*)d_in[0];
    const int*   patterns     = (const int*)d_in[1];
    const float* ff           = (const float*)d_in[2];
    const float* inter_emb    = (const float*)d_in[3];
    const float* pattern_emb  = (const float*)d_in[4];
    const float* feat_W       = (const float*)d_in[5];
    const float* feat_b       = (const float*)d_in[6];
    const float* in_W         = (const float*)d_in[7];
    const float* in_b         = (const float*)d_in[8];
    const float* time_W       = (const float*)d_in[9];
    const float* time_b       = (const float*)d_in[10];
    const float* pos_W        = (const float*)d_in[11];
    const float* pos_b        = (const float*)d_in[12];
    const float* Wq           = (const float*)d_in[13];
    const float* bq           = (const float*)d_in[14];
    const float* Wk           = (const float*)d_in[15];
    const float* bk           = (const float*)d_in[16];
    const float* Wv           = (const float*)d_in[17];
    const float* bv           = (const float*)d_in[18];
    const float* Wo           = (const float*)d_in[19];
    const float* bo           = (const float*)d_in[20];
    const float* kerple_p     = (const float*)d_in[21];
    const float* kerple_a     = (const float*)d_in[22];
    const float* ln1_g        = (const float*)d_in[23];
    const float* ln1_b        = (const float*)d_in[24];
    const float* ln2_g        = (const float*)d_in[25];
    const float* ln2_b        = (const float*)d_in[26];
    const float* ffn_W1       = (const float*)d_in[27];
    const float* ffn_b1       = (const float*)d_in[28];
    const float* ffn_W2       = (const float*)d_in[29];
    const float* ffn_b2       = (const float*)d_in[30];
    const float* out_W        = (const float*)d_in[31];
    const float* out_b        = (const float*)d_in[32];
    float* out = (float*)d_out;

    // ---- workspace layout (bytes) ----
    char* wsb = (char*)d_ws;
    const size_t MB = 1024 * 1024;
    float*    x    = (float*)(wsb + 0);          //  8 MB fp32 activations
    float*    tmp  = (float*)(wsb + 8  * MB);    //  8 MB fp32 residual branch
    ushort_t* xb   = (ushort_t*)(wsb + 16 * MB); //  4 MB bf16 copy of x
    ushort_t* qbuf = (ushort_t*)(wsb + 20 * MB); //  4 MB bf16 Q (B,H,S,DH)
    ushort_t* kbuf = (ushort_t*)(wsb + 24 * MB); //  4 MB bf16 K (B,H,S,DH)
    ushort_t* vtbf = (ushort_t*)(wsb + 28 * MB); //  4 MB bf16 V^T (B,H,DH,S)
    ushort_t* shrd = (ushort_t*)(wsb + 32 * MB); // 16 MB: cbuf / o_bf / h_bf
    ushort_t* cbuf = shrd;                        // 8192x384 bf16
    ushort_t* o_bf = shrd;                        // 8192x256 bf16
    ushort_t* h_bf = shrd;                        // 8192x1024 bf16
    char* wp = wsb + 48 * MB;
    ushort_t* inWt  = (ushort_t*)wp;  wp += 256  * 384 * 2;       // [256][384]
    ushort_t* qkvWt = (ushort_t*)wp;  wp += 2 * 768 * 256 * 2;    // [l][768][256]
    ushort_t* WoT   = (ushort_t*)wp;  wp += 2 * 256 * 256 * 2;    // [l][256][256]
    ushort_t* W1T   = (ushort_t*)wp;  wp += 2 * 1024 * 256 * 2;   // [l][1024][256]
    ushort_t* W2T   = (ushort_t*)wp;  wp += 2 * 256 * 1024 * 2;   // [l][256][1024]
    ushort_t* outWt = (ushort_t*)wp;  wp += 2048 * 256 * 2;       // [2048][256] zero-pad

    // ---- weight conversion (transpose -> bf16) ----
    ConvArgs ca;
    int D2 = 256 * 256;
    ca.s[0]  = { in_W,              inWt,               384,  256,  256 };
    ca.s[1]  = { Wq,                qkvWt,              256,  256,  256 };
    ca.s[2]  = { Wk,                qkvWt + 1 * D2,     256,  256,  256 };
    ca.s[3]  = { Wv,                qkvWt + 2 * D2,     256,  256,  256 };
    ca.s[4]  = { Wq + D2,           qkvWt + 3 * D2,     256,  256,  256 };
    ca.s[5]  = { Wk + D2,           qkvWt + 4 * D2,     256,  256,  256 };
    ca.s[6]  = { Wv + D2,           qkvWt + 5 * D2,     256,  256,  256 };
    ca.s[7]  = { Wo,                WoT,                256,  256,  256 };
    ca.s[8]  = { Wo + D2,           WoT + D2,           256,  256,  256 };
    ca.s[9]  = { ffn_W1,            W1T,                256,  1024, 1024 };
    ca.s[10] = { ffn_W1 + 4 * D2,   W1T + 4 * D2,       256,  1024, 1024 };
    ca.s[11] = { ffn_W2,            W2T,                1024, 256,  256 };
    ca.s[12] = { ffn_W2 + 4 * D2,   W2T + 4 * D2,       1024, 256,  256 };
    ca.s[13] = { out_W,             outWt,              256,  2000, 2048 };
    convert_kernel<<<dim3(2048, 14), 256, 0, stream>>>(ca);

    // ---- input projection + encodings ----
    concat_kernel<<<NTOK, 384, 0, stream>>>(interactions, patterns, ff,
                                            inter_emb, pattern_emb, feat_W, feat_b, cbuf);
    gemm_bf16<<<dim3(4, 64), 256, 0, stream>>>(cbuf, inWt, NTOK, 256, 384, 0,
                                               x, nullptr, nullptr, nullptr,
                                               in_b, nullptr, nullptr, 0);
    addenc_kernel<<<NTOK, 256, 0, stream>>>(x, xb, ff, time_W, time_b, pos_W, pos_b);

    for (int l = 0; l < 2; l++) {
        gemm_bf16<<<dim3(12, 64), 256, 0, stream>>>(
            xb, qkvWt + (size_t)l * 768 * 256, NTOK, 768, 256, 2,
            nullptr, qbuf, kbuf, vtbf,
            bq + l * 256, bk + l * 256, bv + l * 256, 0);
        attn_mfma<<<dim3(32, NHD, BATCH), 256, 0, stream>>>(
            qbuf, kbuf, vtbf, kerple_p + l * NHD, kerple_a + l * NHD, o_bf);
        gemm_bf16<<<dim3(4, 64), 256, 0, stream>>>(
            o_bf, WoT + (size_t)l * D2, NTOK, 256, 256, 0,
            tmp, nullptr, nullptr, nullptr, bo + l * 256, nullptr, nullptr, 0);
        ln_kernel<<<NTOK, 256, 0, stream>>>(x, tmp, ln1_g + l * 256, ln1_b + l * 256, xb);
        gemm_bf16<<<dim3(16, 64), 256, 0, stream>>>(
            xb, W1T + (size_t)l * 4 * D2, NTOK, 1024, 256, 1,
            nullptr, h_bf, nullptr, nullptr, ffn_b1 + l * 1024, nullptr, nullptr, 0);
        gemm_bf16<<<dim3(4, 64), 256, 0, stream>>>(
            h_bf, W2T + (size_t)l * 4 * D2, NTOK, 256, 1024, 0,
            tmp, nullptr, nullptr, nullptr, ffn_b2 + l * 256, nullptr, nullptr, 0);
        ln_kernel<<<NTOK, 256, 0, stream>>>(x, tmp, ln2_g + l * 256, ln2_b + l * 256, xb);
    }

    // ---- output projection (N=2000, padded weight rows to 2048) ----
    gemm_bf16<<<dim3(32, 64), 256, 0, stream>>>(
        xb, outWt, NTOK, 2048, 256, 3,
        out, nullptr, nullptr, nullptr, out_b, nullptr, nullptr, NSKC);
}

// Round 4
// 488.573 us; speedup vs baseline: 7.6144x; 1.1202x over previous
//
#include <hip/hip_runtime.h>
#include <math.h>

// B=4, S=2048, F=8, D=256, H=8, L=2, FF=1024, NSK=2000
#define SEQ   2048
#define BATCH 4
#define NTOK  8192
#define DM    256
#define NHD   8
#define DHD   32
#define DFF   1024
#define NSKC  2000

typedef __attribute__((ext_vector_type(8))) short short8;
typedef __attribute__((ext_vector_type(4))) float f32x4;
typedef unsigned short ushort_t;

__device__ __forceinline__ ushort_t f2bf(float x) {
    union { float f; unsigned u; } c; c.f = x;
    unsigned r = c.u + 0x7FFFu + ((c.u >> 16) & 1u);
    return (ushort_t)(r >> 16);
}

// ---------------------------------------------------------------------------
// Weight conversion: dst[n][k] = bf16(src[k][n]) (transpose), zero-pad n>=N.
// ---------------------------------------------------------------------------
struct ConvSeg { const float* src; ushort_t* dst; int K; int N; int Npad; };
struct ConvArgs { ConvSeg s[14]; };

__global__ __launch_bounds__(256) void convert_kernel(ConvArgs args) {
    ConvSeg sg = args.s[blockIdx.y];
    int e = blockIdx.x * 256 + threadIdx.x;
    int tot = sg.Npad * sg.K;
    if (e >= tot) return;
    int n = e / sg.K;
    int k = e - n * sg.K;
    float v = (n < sg.N) ? sg.src[(size_t)k * sg.N + n] : 0.0f;
    sg.dst[e] = f2bf(v);
}

// ---------------------------------------------------------------------------
// concat row [inter_e(256) | pat_e(64) | feat_e(64)] -> bf16
// ---------------------------------------------------------------------------
__global__ __launch_bounds__(384) void concat_kernel(
    const int* __restrict__ interactions, const int* __restrict__ patterns,
    const float* __restrict__ ff, const float* __restrict__ inter_emb,
    const float* __restrict__ pattern_emb, const float* __restrict__ feat_W,
    const float* __restrict__ feat_b, ushort_t* __restrict__ out)
{
    int tok = blockIdx.x;
    int j = threadIdx.x;
    float v;
    if (j < 256) {
        v = inter_emb[(size_t)interactions[tok] * 256 + j];
    } else if (j < 320) {
        v = pattern_emb[patterns[tok] * 64 + (j - 256)];
    } else {
        int c = j - 320;
        float acc = feat_b[c];
#pragma unroll
        for (int f = 0; f < 8; f++) acc += ff[tok * 8 + f] * feat_W[f * 64 + c];
        v = acc;
    }
    out[(size_t)tok * 384 + j] = f2bf(v);
}

// ---------------------------------------------------------------------------
// x += tanh(el*time_W+time_b) + pos*pos_W+pos_b ; write fp32 + bf16 copies
// ---------------------------------------------------------------------------
__global__ __launch_bounds__(256) void addenc_kernel(
    float* __restrict__ x, ushort_t* __restrict__ xb, const float* __restrict__ ff,
    const float* __restrict__ time_W, const float* __restrict__ time_b,
    const float* __restrict__ pos_W, const float* __restrict__ pos_b)
{
    int tok = blockIdx.x;
    int d = threadIdx.x;
    int s = tok & (SEQ - 1);
    float el = ff[tok * 8];
    float te = tanhf(el * time_W[d] + time_b[d]);
    float pe = ((float)s * (1.0f / (float)SEQ)) * pos_W[d] + pos_b[d];
    size_t idx = (size_t)tok * DM + d;
    float nv = x[idx] + te + pe;
    x[idx] = nv;
    xb[idx] = f2bf(nv);
}

// ---------------------------------------------------------------------------
// LayerNorm(x + r) in place; also writes bf16 copy.
// ---------------------------------------------------------------------------
__global__ __launch_bounds__(256) void ln_kernel(
    float* __restrict__ x, const float* __restrict__ r,
    const float* __restrict__ g, const float* __restrict__ b,
    ushort_t* __restrict__ xb)
{
    int tok = blockIdx.x;
    int d = threadIdx.x;
    size_t idx = (size_t)tok * DM + d;
    float v = x[idx] + r[idx];
    float s1 = v, s2 = v * v;
#pragma unroll
    for (int off = 32; off > 0; off >>= 1) {
        s1 += __shfl_down(s1, off, 64);
        s2 += __shfl_down(s2, off, 64);
    }
    __shared__ float red1[4], red2[4];
    int wid = d >> 6, lane = d & 63;
    if (lane == 0) { red1[wid] = s1; red2[wid] = s2; }
    __syncthreads();
    s1 = red1[0] + red1[1] + red1[2] + red1[3];
    s2 = red2[0] + red2[1] + red2[2] + red2[3];
    float mean = s1 * (1.0f / 256.0f);
    float var = s2 * (1.0f / 256.0f) - mean * mean;
    float inv = rsqrtf(var + 1e-6f);
    float nv = g[d] * (v - mean) * inv + b[d];
    x[idx] = nv;
    xb[idx] = f2bf(nv);
}

// ---------------------------------------------------------------------------
// bf16 MFMA GEMM: C[M,N] = A[M,K](bf16,row-major) @ Bt[N,K](bf16)^T + bias.
// BM=128, BN=64, BK=32; 4 waves, each 32(m)x64(n), 8 mfma/iter. Register
// prefetch of the next K-tile overlaps global latency with mfma.
// mode 0: fp32 out + bias   mode 2: QKV epilogue (q,k (B,H,S,DH); v^T)
// ---------------------------------------------------------------------------
__global__ __launch_bounds__(256) void gemm_bf16(
    const ushort_t* __restrict__ A, const ushort_t* __restrict__ Bt,
    int M, int N, int K, int mode,
    float* __restrict__ Cf, ushort_t* __restrict__ Cb,
    ushort_t* __restrict__ Ck, ushort_t* __restrict__ Cv,
    const float* __restrict__ b0, const float* __restrict__ b1,
    const float* __restrict__ b2)
{
    __shared__ ushort_t As[128][40];
    __shared__ ushort_t Bs[64][40];
    int m0 = blockIdx.y * 128, n0 = blockIdx.x * 64;
    int tid = threadIdx.x;
    int wv = tid >> 6, lane = tid & 63;
    int quad = lane >> 4, l16 = lane & 15;
    int srow = tid >> 2, sc = (tid & 3) << 3;

    f32x4 acc[2][4];
#pragma unroll
    for (int i = 0; i < 2; i++)
#pragma unroll
        for (int j = 0; j < 4; j++) acc[i][j] = (f32x4){0.f, 0.f, 0.f, 0.f};

    uint4 pa0 = *(const uint4*)&A[(size_t)(m0 + srow) * K + sc];
    uint4 pa1 = *(const uint4*)&A[(size_t)(m0 + 64 + srow) * K + sc];
    uint4 pbb = *(const uint4*)&Bt[(size_t)(n0 + srow) * K + sc];

    int msub = wv * 32;
    for (int k0 = 0; k0 < K; k0 += 32) {
        __syncthreads();
        *(uint4*)&As[srow][sc] = pa0;
        *(uint4*)&As[64 + srow][sc] = pa1;
        *(uint4*)&Bs[srow][sc] = pbb;
        __syncthreads();
        if (k0 + 32 < K) {
            pa0 = *(const uint4*)&A[(size_t)(m0 + srow) * K + k0 + 32 + sc];
            pa1 = *(const uint4*)&A[(size_t)(m0 + 64 + srow) * K + k0 + 32 + sc];
            pbb = *(const uint4*)&Bt[(size_t)(n0 + srow) * K + k0 + 32 + sc];
        }
        short8 af0 = *(const short8*)&As[msub + l16][quad * 8];
        short8 af1 = *(const short8*)&As[msub + 16 + l16][quad * 8];
        short8 bf0 = *(const short8*)&Bs[l16][quad * 8];
        short8 bf1 = *(const short8*)&Bs[16 + l16][quad * 8];
        short8 bf2 = *(const short8*)&Bs[32 + l16][quad * 8];
        short8 bf3 = *(const short8*)&Bs[48 + l16][quad * 8];
        acc[0][0] = __builtin_amdgcn_mfma_f32_16x16x32_bf16(af0, bf0, acc[0][0], 0, 0, 0);
        acc[0][1] = __builtin_amdgcn_mfma_f32_16x16x32_bf16(af0, bf1, acc[0][1], 0, 0, 0);
        acc[0][2] = __builtin_amdgcn_mfma_f32_16x16x32_bf16(af0, bf2, acc[0][2], 0, 0, 0);
        acc[0][3] = __builtin_amdgcn_mfma_f32_16x16x32_bf16(af0, bf3, acc[0][3], 0, 0, 0);
        acc[1][0] = __builtin_amdgcn_mfma_f32_16x16x32_bf16(af1, bf0, acc[1][0], 0, 0, 0);
        acc[1][1] = __builtin_amdgcn_mfma_f32_16x16x32_bf16(af1, bf1, acc[1][1], 0, 0, 0);
        acc[1][2] = __builtin_amdgcn_mfma_f32_16x16x32_bf16(af1, bf2, acc[1][2], 0, 0, 0);
        acc[1][3] = __builtin_amdgcn_mfma_f32_16x16x32_bf16(af1, bf3, acc[1][3], 0, 0, 0);
    }

#pragma unroll
    for (int mt = 0; mt < 2; mt++) {
#pragma unroll
        for (int nt = 0; nt < 4; nt++) {
            int n = n0 + nt * 16 + l16;
#pragma unroll
            for (int r = 0; r < 4; r++) {
                int m = m0 + msub + mt * 16 + quad * 4 + r;
                float v = acc[mt][nt][r];
                if (mode == 0) {
                    Cf[(size_t)m * N + n] = v + b0[n];
                } else {
                    int which = n >> 8, idx = n & 255;
                    int hh = idx >> 5, d = idx & 31;
                    int s = m & (SEQ - 1), b = m >> 11;
                    if (which == 0)
                        Cb[(((size_t)(b * NHD + hh)) * SEQ + s) * DHD + d] = f2bf(v + b0[idx]);
                    else if (which == 1)
                        Ck[(((size_t)(b * NHD + hh)) * SEQ + s) * DHD + d] = f2bf(v + b1[idx]);
                    else
                        Cv[(((size_t)(b * NHD + hh)) * DHD + d) * SEQ + s] = f2bf(v + b2[idx]);
                }
            }
        }
    }
}

// ---------------------------------------------------------------------------
// bf16 MFMA GEMM, BM=128 BN=128 BK=32: 4 waves, each 64x64, 16 mfma/iter.
// mode 1: gelu -> bf16 out    mode 3: fp32 + bias, col guard n < Nreal
// ---------------------------------------------------------------------------
__global__ __launch_bounds__(256) void gemm_bf16_128(
    const ushort_t* __restrict__ A, const ushort_t* __restrict__ Bt,
    int M, int N, int K, int mode,
    float* __restrict__ Cf, ushort_t* __restrict__ Cb,
    const float* __restrict__ b0, int Nreal)
{
    __shared__ ushort_t As[128][40];
    __shared__ ushort_t Bs[128][40];
    int m0 = blockIdx.y * 128, n0 = blockIdx.x * 128;
    int tid = threadIdx.x;
    int wv = tid >> 6, lane = tid & 63;
    int quad = lane >> 4, l16 = lane & 15;
    int wm = (wv >> 1) * 64, wn = (wv & 1) * 64;
    int srow = tid >> 1, sc = (tid & 1) << 4;   // 2x uint4 per thread per tile

    f32x4 acc[4][4];
#pragma unroll
    for (int i = 0; i < 4; i++)
#pragma unroll
        for (int j = 0; j < 4; j++) acc[i][j] = (f32x4){0.f, 0.f, 0.f, 0.f};

    uint4 pa0 = *(const uint4*)&A[(size_t)(m0 + srow) * K + sc];
    uint4 pa1 = *(const uint4*)&A[(size_t)(m0 + srow) * K + sc + 8];
    uint4 pb0 = *(const uint4*)&Bt[(size_t)(n0 + srow) * K + sc];
    uint4 pb1 = *(const uint4*)&Bt[(size_t)(n0 + srow) * K + sc + 8];

    for (int k0 = 0; k0 < K; k0 += 32) {
        __syncthreads();
        *(uint4*)&As[srow][sc] = pa0;
        *(uint4*)&As[srow][sc + 8] = pa1;
        *(uint4*)&Bs[srow][sc] = pb0;
        *(uint4*)&Bs[srow][sc + 8] = pb1;
        __syncthreads();
        if (k0 + 32 < K) {
            pa0 = *(const uint4*)&A[(size_t)(m0 + srow) * K + k0 + 32 + sc];
            pa1 = *(const uint4*)&A[(size_t)(m0 + srow) * K + k0 + 32 + sc + 8];
            pb0 = *(const uint4*)&Bt[(size_t)(n0 + srow) * K + k0 + 32 + sc];
            pb1 = *(const uint4*)&Bt[(size_t)(n0 + srow) * K + k0 + 32 + sc + 8];
        }
        short8 af[4], bf[4];
#pragma unroll
        for (int i = 0; i < 4; i++) {
            af[i] = *(const short8*)&As[wm + i * 16 + l16][quad * 8];
            bf[i] = *(const short8*)&Bs[wn + i * 16 + l16][quad * 8];
        }
#pragma unroll
        for (int i = 0; i < 4; i++)
#pragma unroll
            for (int j = 0; j < 4; j++)
                acc[i][j] = __builtin_amdgcn_mfma_f32_16x16x32_bf16(af[i], bf[j], acc[i][j], 0, 0, 0);
    }

#pragma unroll
    for (int i = 0; i < 4; i++) {
#pragma unroll
        for (int j = 0; j < 4; j++) {
            int n = n0 + wn + j * 16 + l16;
#pragma unroll
            for (int r = 0; r < 4; r++) {
                int m = m0 + wm + i * 16 + quad * 4 + r;
                float v = acc[i][j][r];
                if (mode == 1) {
                    float t = v + b0[n];
                    t = 0.5f * t * (1.0f + erff(t * 0.70710678118654752f));
                    Cb[(size_t)m * N + n] = f2bf(t);
                } else {
                    if (n < Nreal) Cf[(size_t)m * Nreal + n] = v + b0[n];
                }
            }
        }
    }
}

// ---------------------------------------------------------------------------
// MFMA flash attention, paired-tile waves for load balance.
// Wave w of block bx handles q-tiles (j, 127-j), j = bx*4+w: every wave runs
// ~65 tile-chunks, and K/V fragment loads for the hi tile are shared with the
// lo tile. Interior chunks (k0+31 <= q0, wave-uniform) take a guard-free
// epilogue. P round-trip per tile via per-wave LDS (in-wave lgkmcnt wait, no
// block barrier). Q,K bf16 (B,H,S,DH); V^T bf16 (B,H,DH,S); out bf16.
// ---------------------------------------------------------------------------
__global__ __launch_bounds__(256) void attn_mfma(
    const ushort_t* __restrict__ qb, const ushort_t* __restrict__ kb,
    const ushort_t* __restrict__ vtb, const float* __restrict__ kp,
    const float* __restrict__ ka, ushort_t* __restrict__ ob)
{
    int h = blockIdx.y, b = blockIdx.z;
    int tid = threadIdx.x, wv = tid >> 6, lane = tid & 63;
    int quad = lane >> 4, l16 = lane & 15;
    __shared__ float tab[SEQ];
    __shared__ ushort_t P[4][2][16 * 40];

    float pp = log1pf(__expf(kp[h]));    // softplus
    float aa = log1pf(__expf(ka[h]));
    for (int i = tid; i < SEQ; i += 256) tab[i] = -pp * log1pf(aa * (float)i);
    __syncthreads();

    int bh = b * NHD + h;
    const ushort_t* Qh = qb + (size_t)bh * SEQ * DHD;
    const ushort_t* Kh = kb + (size_t)bh * SEQ * DHD;
    const ushort_t* Vh = vtb + (size_t)bh * DHD * SEQ;

    int j = blockIdx.x * 4 + wv;         // 0..63
    int tlo = j, thi = 127 - j;
    int qlo0 = tlo * 16, qhi0 = thi * 16;
    const float scale = 0.17677669529663687f;   // 1/sqrt(32)

    short8 qfl = *(const short8*)&Qh[(qlo0 + l16) * DHD + quad * 8];
    short8 qfh = *(const short8*)&Qh[(qhi0 + l16) * DHD + quad * 8];
    f32x4 ol0 = (f32x4){0.f,0.f,0.f,0.f}, ol1 = (f32x4){0.f,0.f,0.f,0.f};
    f32x4 oh0 = (f32x4){0.f,0.f,0.f,0.f}, oh1 = (f32x4){0.f,0.f,0.f,0.f};
    float lsl[4] = {0.f,0.f,0.f,0.f}, lsh[4] = {0.f,0.f,0.f,0.f};
    ushort_t* Pl = &P[wv][0][0];
    ushort_t* Ph = &P[wv][1][0];

    int nch_hi = (thi + 2) >> 1;
    int nch_lo = (tlo + 2) >> 1;
    int qsrh = qhi0 + quad * 4;
    int qsrl = qlo0 + quad * 4;

    for (int ch = 0; ch < nch_hi; ch++) {
        int k0 = ch * 32;
        short8 kf0 = *(const short8*)&Kh[(k0 + l16) * DHD + quad * 8];
        short8 kf1 = *(const short8*)&Kh[(k0 + 16 + l16) * DHD + quad * 8];
        short8 vf0 = *(const short8*)&Vh[l16 * SEQ + k0 + quad * 8];
        short8 vf1 = *(const short8*)&Vh[(16 + l16) * SEQ + k0 + quad * 8];
        f32x4 z = (f32x4){0.f,0.f,0.f,0.f};

        // ---- hi tile scores ----
        f32x4 s0 = __builtin_amdgcn_mfma_f32_16x16x32_bf16(qfh, kf0, z, 0, 0, 0);
        f32x4 s1 = __builtin_amdgcn_mfma_f32_16x16x32_bf16(qfh, kf1, z, 0, 0, 0);
        if (k0 + 31 <= qhi0) {           // interior: all 32 keys valid
#pragma unroll
            for (int r = 0; r < 4; r++) {
                const float* tp = &tab[qsrh + r - k0 - l16 - 16];
                float e0 = __expf(s0[r] * scale + tp[16]);
                float e1 = __expf(s1[r] * scale + tp[0]);
                lsh[r] += e0 + e1;
                Ph[(quad * 4 + r) * 40 + l16]      = f2bf(e0);
                Ph[(quad * 4 + r) * 40 + 16 + l16] = f2bf(e1);
            }
        } else {
#pragma unroll
            for (int r = 0; r < 4; r++) {
                int d0 = qsrh + r - k0 - l16;
                int d1 = d0 - 16;
                float e0 = 0.f, e1 = 0.f;
                if (d0 >= 0) e0 = __expf(s0[r] * scale + tab[d0]);
                if (d1 >= 0) e1 = __expf(s1[r] * scale + tab[d1]);
                lsh[r] += e0 + e1;
                Ph[(quad * 4 + r) * 40 + l16]      = f2bf(e0);
                Ph[(quad * 4 + r) * 40 + 16 + l16] = f2bf(e1);
            }
        }

        // ---- lo tile scores (shares K/V frags) ----
        bool do_lo = (ch < nch_lo);
        if (do_lo) {
            f32x4 t0 = __builtin_amdgcn_mfma_f32_16x16x32_bf16(qfl, kf0, z, 0, 0, 0);
            f32x4 t1 = __builtin_amdgcn_mfma_f32_16x16x32_bf16(qfl, kf1, z, 0, 0, 0);
            if (k0 + 31 <= qlo0) {
#pragma unroll
                for (int r = 0; r < 4; r++) {
                    const float* tp = &tab[qsrl + r - k0 - l16 - 16];
                    float e0 = __expf(t0[r] * scale + tp[16]);
                    float e1 = __expf(t1[r] * scale + tp[0]);
                    lsl[r] += e0 + e1;
                    Pl[(quad * 4 + r) * 40 + l16]      = f2bf(e0);
                    Pl[(quad * 4 + r) * 40 + 16 + l16] = f2bf(e1);
                }
            } else {
#pragma unroll
                for (int r = 0; r < 4; r++) {
                    int d0 = qsrl + r - k0 - l16;
                    int d1 = d0 - 16;
                    float e0 = 0.f, e1 = 0.f;
                    if (d0 >= 0) e0 = __expf(t0[r] * scale + tab[d0]);
                    if (d1 >= 0) e1 = __expf(t1[r] * scale + tab[d1]);
                    lsl[r] += e0 + e1;
                    Pl[(quad * 4 + r) * 40 + l16]      = f2bf(e0);
                    Pl[(quad * 4 + r) * 40 + 16 + l16] = f2bf(e1);
                }
            }
        }

        __builtin_amdgcn_s_waitcnt(0xC07F);     // lgkmcnt(0): P writes visible
        __builtin_amdgcn_wave_barrier();        // pin write->read order
        short8 pfh = *(const short8*)&Ph[l16 * 40 + quad * 8];
        oh0 = __builtin_amdgcn_mfma_f32_16x16x32_bf16(pfh, vf0, oh0, 0, 0, 0);
        oh1 = __builtin_amdgcn_mfma_f32_16x16x32_bf16(pfh, vf1, oh1, 0, 0, 0);
        if (do_lo) {
            short8 pfl = *(const short8*)&Pl[l16 * 40 + quad * 8];
            ol0 = __builtin_amdgcn_mfma_f32_16x16x32_bf16(pfl, vf0, ol0, 0, 0, 0);
            ol1 = __builtin_amdgcn_mfma_f32_16x16x32_bf16(pfl, vf1, ol1, 0, 0, 0);
        }
    }

#pragma unroll
    for (int r = 0; r < 4; r++) {
#pragma unroll
        for (int off = 1; off < 16; off <<= 1) {
            lsh[r] += __shfl_xor(lsh[r], off, 16);
            lsl[r] += __shfl_xor(lsl[r], off, 16);
        }
    }
#pragma unroll
    for (int r = 0; r < 4; r++) {
        float rh = 1.0f / lsh[r];
        float rl = 1.0f / lsl[r];
        size_t bh_ = ((size_t)(b * SEQ + qsrh + r)) * DM + h * DHD;
        size_t bl_ = ((size_t)(b * SEQ + qsrl + r)) * DM + h * DHD;
        ob[bh_ + l16]      = f2bf(oh0[r] * rh);
        ob[bh_ + 16 + l16] = f2bf(oh1[r] * rh);
        ob[bl_ + l16]      = f2bf(ol0[r] * rl);
        ob[bl_ + 16 + l16] = f2bf(ol1[r] * rl);
    }
}

// ---------------------------------------------------------------------------
extern "C" void kernel_launch(void* const* d_in, const int* in_sizes, int n_in,
                              void* d_out, int out_size, void* d_ws, size_t ws_size,
                              hipStream_t stream) {
    const int*   interactions = (const int*)d_in[0];
    const int*   patterns     = (const int*)d_in[1];
    const float* ff           = (const float*)d_in[2];
    const float* inter_emb    = (const float*)d_in[3];
    const float* pattern_emb  = (const float*)d_in[4];
    const float* feat_W       = (const float*)d_in[5];
    const float* feat_b       = (const float*)d_in[6];
    const float* in_W         = (const float*)d_in[7];
    const float* in_b         = (const float*)d_in[8];
    const float* time_W       = (const float*)d_in[9];
    const float* time_b       = (const float*)d_in[10];
    const float* pos_W        = (const float*)d_in[11];
    const float* pos_b        = (const float*)d_in[12];
    const float* Wq           = (const float*)d_in[13];
    const float* bq           = (const float*)d_in[14];
    const float* Wk           = (const float*)d_in[15];
    const float* bk           = (const float*)d_in[16];
    const float* Wv           = (const float*)d_in[17];
    const float* bv           = (const float*)d_in[18];
    const float* Wo           = (const float*)d_in[19];
    const float* bo           = (const float*)d_in[20];
    const float* kerple_p     = (const float*)d_in[21];
    const float* kerple_a     = (const float*)d_in[22];
    const float* ln1_g        = (const float*)d_in[23];
    const float* ln1_b        = (const float*)d_in[24];
    const float* ln2_g        = (const float*)d_in[25];
    const float* ln2_b        = (const float*)d_in[26];
    const float* ffn_W1       = (const float*)d_in[27];
    const float* ffn_b1       = (const float*)d_in[28];
    const float* ffn_W2       = (const float*)d_in[29];
    const float* ffn_b2       = (const float*)d_in[30];
    const float* out_W        = (const float*)d_in[31];
    const float* out_b        = (const float*)d_in[32];
    float* out = (float*)d_out;

    // ---- workspace layout (bytes) ----
    char* wsb = (char*)d_ws;
    const size_t MB = 1024 * 1024;
    float*    x    = (float*)(wsb + 0);          //  8 MB fp32 activations
    float*    tmp  = (float*)(wsb + 8  * MB);    //  8 MB fp32 residual branch
    ushort_t* xb   = (ushort_t*)(wsb + 16 * MB); //  4 MB bf16 copy of x
    ushort_t* qbuf = (ushort_t*)(wsb + 20 * MB); //  4 MB bf16 Q (B,H,S,DH)
    ushort_t* kbuf = (ushort_t*)(wsb + 24 * MB); //  4 MB bf16 K (B,H,S,DH)
    ushort_t* vtbf = (ushort_t*)(wsb + 28 * MB); //  4 MB bf16 V^T (B,H,DH,S)
    ushort_t* shrd = (ushort_t*)(wsb + 32 * MB); // 16 MB: cbuf / o_bf / h_bf
    ushort_t* cbuf = shrd;                        // 8192x384 bf16
    ushort_t* o_bf = shrd;                        // 8192x256 bf16
    ushort_t* h_bf = shrd;                        // 8192x1024 bf16
    char* wp = wsb + 48 * MB;
    ushort_t* inWt  = (ushort_t*)wp;  wp += 256  * 384 * 2;       // [256][384]
    ushort_t* qkvWt = (ushort_t*)wp;  wp += 2 * 768 * 256 * 2;    // [l][768][256]
    ushort_t* WoT   = (ushort_t*)wp;  wp += 2 * 256 * 256 * 2;    // [l][256][256]
    ushort_t* W1T   = (ushort_t*)wp;  wp += 2 * 1024 * 256 * 2;   // [l][1024][256]
    ushort_t* W2T   = (ushort_t*)wp;  wp += 2 * 256 * 1024 * 2;   // [l][256][1024]
    ushort_t* outWt = (ushort_t*)wp;  wp += 2048 * 256 * 2;       // [2048][256] zero-pad

    // ---- weight conversion (transpose -> bf16) ----
    ConvArgs ca;
    int D2 = 256 * 256;
    ca.s[0]  = { in_W,              inWt,               384,  256,  256 };
    ca.s[1]  = { Wq,                qkvWt,              256,  256,  256 };
    ca.s[2]  = { Wk,                qkvWt + 1 * D2,     256,  256,  256 };
    ca.s[3]  = { Wv,                qkvWt + 2 * D2,     256,  256,  256 };
    ca.s[4]  = { Wq + D2,           qkvWt + 3 * D2,     256,  256,  256 };
    ca.s[5]  = { Wk + D2,           qkvWt + 4 * D2,     256,  256,  256 };
    ca.s[6]  = { Wv + D2,           qkvWt + 5 * D2,     256,  256,  256 };
    ca.s[7]  = { Wo,                WoT,                256,  256,  256 };
    ca.s[8]  = { Wo + D2,           WoT + D2,           256,  256,  256 };
    ca.s[9]  = { ffn_W1,            W1T,                256,  1024, 1024 };
    ca.s[10] = { ffn_W1 + 4 * D2,   W1T + 4 * D2,       256,  1024, 1024 };
    ca.s[11] = { ffn_W2,            W2T,                1024, 256,  256 };
    ca.s[12] = { ffn_W2 + 4 * D2,   W2T + 4 * D2,       1024, 256,  256 };
    ca.s[13] = { out_W,             outWt,              256,  2000, 2048 };
    convert_kernel<<<dim3(2048, 14), 256, 0, stream>>>(ca);

    // ---- input projection + encodings ----
    concat_kernel<<<NTOK, 384, 0, stream>>>(interactions, patterns, ff,
                                            inter_emb, pattern_emb, feat_W, feat_b, cbuf);
    gemm_bf16<<<dim3(4, 64), 256, 0, stream>>>(cbuf, inWt, NTOK, 256, 384, 0,
                                               x, nullptr, nullptr, nullptr,
                                               in_b, nullptr, nullptr);
    addenc_kernel<<<NTOK, 256, 0, stream>>>(x, xb, ff, time_W, time_b, pos_W, pos_b);

    for (int l = 0; l < 2; l++) {
        gemm_bf16<<<dim3(12, 64), 256, 0, stream>>>(
            xb, qkvWt + (size_t)l * 768 * 256, NTOK, 768, 256, 2,
            nullptr, qbuf, kbuf, vtbf,
            bq + l * 256, bk + l * 256, bv + l * 256);
        attn_mfma<<<dim3(16, NHD, BATCH), 256, 0, stream>>>(
            qbuf, kbuf, vtbf, kerple_p + l * NHD, kerple_a + l * NHD, o_bf);
        gemm_bf16<<<dim3(4, 64), 256, 0, stream>>>(
            o_bf, WoT + (size_t)l * D2, NTOK, 256, 256, 0,
            tmp, nullptr, nullptr, nullptr, bo + l * 256, nullptr, nullptr);
        ln_kernel<<<NTOK, 256, 0, stream>>>(x, tmp, ln1_g + l * 256, ln1_b + l * 256, xb);
        gemm_bf16_128<<<dim3(8, 64), 256, 0, stream>>>(
            xb, W1T + (size_t)l * 4 * D2, NTOK, 1024, 256, 1,
            nullptr, h_bf, ffn_b1 + l * 1024, 1024);
        gemm_bf16<<<dim3(4, 64), 256, 0, stream>>>(
            h_bf, W2T + (size_t)l * 4 * D2, NTOK, 256, 1024, 0,
            tmp, nullptr, nullptr, nullptr, ffn_b2 + l * 256, nullptr, nullptr);
        ln_kernel<<<NTOK, 256, 0, stream>>>(x, tmp, ln2_g + l * 256, ln2_b + l * 256, xb);
    }

    // ---- output projection (N=2048 padded, guard to 2000) ----
    gemm_bf16_128<<<dim3(16, 64), 256, 0, stream>>>(
        xb, outWt, NTOK, 2048, 256, 3,
        out, nullptr, out_b, NSKC);
}